// Round 6
// baseline (196.968 us; speedup 1.0000x reference)
//
#include <hip/hip_runtime.h>
#include <math.h>

#define NB 64
#define LIN 4001
#define LC 998
#define ND 1000
#define EPSBN 1e-5f

#define CKL 100          // K-chunk for QKV GEMM -> 10 chunks * 48 = 480 blocks
#define NCHL 10
#define CKO 50           // K-chunk for out GEMM -> 20 chunks * 16 = 320 blocks
#define NCHO 20

// ws float offsets
#define OFF_PP    0u          // 10*3*16*4096 = 1966080
#define OFF_CF    1966080u    // 1000*64      = 64000
#define OFF_OP    2030080u    // 20*16*4096   = 1310720
// end = 3340800 floats = 13.4 MB

// ---------------- shared GEMM microtile body (64b x 64d x CKT) --------------
// (A staged from global; used by k_out. k_lin inlines a conv-fused variant.)
template <int CKT>
__device__ __forceinline__ void gemm_tile(
    const float* __restrict__ Asrc,   // [jc][64] chunk, b-contiguous
    const float* __restrict__ Brow,   // weight base, row stride ldB
    int ldB, int dgb, int j0, int jc,
    float* __restrict__ Pt,           // output tile [64 b][64 d]
    float* lds)
{
    constexpr int LDW = CKT + 1;
    constexpr int F2R = CKT / 2;
    float* ldsC = lds;                // [CKT][64]
    float* ldsW = lds + CKT * 64;     // [64][LDW]
    int tid  = threadIdx.x;
    int lane = tid & 63;
    int w    = tid >> 6;
    int b0   = (lane & 7) << 3;
    int d0   = (lane >> 3) << 3;

    {   // stage A chunk via float4 (fully coalesced)
        const float4* src = (const float4*)Asrc;
        float4* dst = (float4*)ldsC;
        int n = jc * 16;
        for (int t = tid; t < n; t += 256) dst[t] = src[t];
    }
    // stage B tile via float2 (row starts & j0 are even)
    for (int idx = tid; idx < 64 * F2R; idx += 256) {
        int dd = idx / F2R, j2 = idx % F2R;
        int dg = dgb + dd;
        float2 v = make_float2(0.f, 0.f);
        if (dg < ND && 2 * j2 < jc)
            v = *(const float2*)(Brow + (size_t)dg * ldB + j0 + 2 * j2);
        ldsW[dd * LDW + 2 * j2]     = v.x;
        ldsW[dd * LDW + 2 * j2 + 1] = v.y;
    }
    __syncthreads();

    float acc[8][8];
#pragma unroll
    for (int i = 0; i < 8; ++i)
#pragma unroll
        for (int jx = 0; jx < 8; ++jx) acc[i][jx] = 0.f;

    int js = (jc * w) >> 2;
    int je = (jc * (w + 1)) >> 2;
    for (int jj = js; jj < je; ++jj) {
        float4 c0 = *(const float4*)(ldsC + jj * 64 + b0);
        float4 c1 = *(const float4*)(ldsC + jj * 64 + b0 + 4);
        float cv[8] = {c0.x, c0.y, c0.z, c0.w, c1.x, c1.y, c1.z, c1.w};
        float wv[8];
#pragma unroll
        for (int r = 0; r < 8; ++r) wv[r] = ldsW[(d0 + r) * LDW + jj];
#pragma unroll
        for (int i = 0; i < 8; ++i)
#pragma unroll
            for (int jx = 0; jx < 8; ++jx)
                acc[i][jx] = fmaf(cv[i], wv[jx], acc[i][jx]);
    }
    __syncthreads();   // done with staged data; reuse LDS for reduce

    // two passes (f4 halves of each lane's d-range); per-wave buf [64][36]
    for (int p = 0; p < 2; ++p) {
        float* red = lds + w * 2304;
#pragma unroll
        for (int i = 0; i < 8; ++i)
            *(float4*)(red + (b0 + i) * 36 + (d0 >> 1)) =
                make_float4(acc[i][4*p], acc[i][4*p+1], acc[i][4*p+2], acc[i][4*p+3]);
        __syncthreads();
        for (int t = tid; t < 512; t += 256) {
            int bb = t >> 3, gg = t & 7;
            int o = bb * 36 + 4 * gg;
            float4 a0 = *(const float4*)(lds + o);
            float4 a1 = *(const float4*)(lds + 2304 + o);
            float4 a2 = *(const float4*)(lds + 4608 + o);
            float4 a3 = *(const float4*)(lds + 6912 + o);
            float4 s;
            s.x = a0.x + a1.x + a2.x + a3.x;
            s.y = a0.y + a1.y + a2.y + a3.y;
            s.z = a0.z + a1.z + a2.z + a3.z;
            s.w = a0.w + a1.w + a2.w + a3.w;
            *(float4*)(Pt + bb * 64 + 8 * gg + 4 * p) = s;
        }
        __syncthreads();
    }
}

// ---------------- K1: conv-fused QKV GEMM partials -> Pp --------------------
// Each block recomputes its A-chunk (BN+conv for its j-range, all 64 b)
// directly from x into LDS, then runs the proven microtile body.
__global__ __launch_bounds__(256) void k_lin(
    const float* __restrict__ x,
    const float* __restrict__ g, const float* __restrict__ be,
    const float* __restrict__ mu, const float* __restrict__ va,
    const float* __restrict__ cwq, const float* __restrict__ cbq,
    const float* __restrict__ cwk, const float* __restrict__ cbk,
    const float* __restrict__ cwv, const float* __restrict__ cbv,
    const float* __restrict__ lwq, const float* __restrict__ lwk,
    const float* __restrict__ lwv,
    float* __restrict__ Pp)
{
    __shared__ float lds[13676];      // ldsC 6400 | ldsW 6464 | bn 812
    float* ldsC = lds;                // [100][64]
    float* ldsW = lds + 6400;         // [64][101]
    float2* bn2 = (float2*)(lds + 12864);   // [406] (sc, sh)

    int tid   = threadIdx.x;
    int dgb   = blockIdx.x * 64;
    int which = blockIdx.y;
    int chunk = blockIdx.z;
    int j0 = chunk * CKL;
    int jc = (LC - j0 < CKL) ? (LC - j0) : CKL;
    const float* lw = (which == 0) ? lwq : ((which == 1) ? lwk : lwv);
    const float* cw = (which == 0) ? cwq : ((which == 1) ? cwk : cwv);
    const float* cb = (which == 0) ? cbq : ((which == 1) ? cbk : cbv);
    float* Pt = Pp + (((size_t)chunk * 3 + which) * 16 + blockIdx.x) * 4096;

    // BN scale/shift table for this chunk's i-range (coalesced)
    int NI = 4 * jc + 6;
    for (int idx = tid; idx < NI; idx += 256) {
        int i = 4 * j0 + idx;
        float sc = g[i] * rsqrtf(va[i] + EPSBN);
        bn2[idx] = make_float2(sc, be[i] - mu[i] * sc);
    }
    // stage B tile via float2 (row starts & j0 are even): 64 rows x 50 f2
    for (int idx = tid; idx < 3200; idx += 256) {
        int dd = idx / 50, j2 = idx % 50;
        int dg = dgb + dd;
        float2 v = make_float2(0.f, 0.f);
        if (dg < ND && 2 * j2 < jc)
            v = *(const float2*)(lw + (size_t)dg * LC + j0 + 2 * j2);
        ldsW[dd * 101 + 2 * j2]     = v.x;
        ldsW[dd * 101 + 2 * j2 + 1] = v.y;
    }
    __syncthreads();

    // conv A-stage: wave w covers jj = w, w+4, ...; lane = batch.
    // LDS writes stride-1 across lanes (conflict-free); x reads row-local.
    {
        int w    = tid >> 6;
        int b    = tid & 63;
        float cw_r[10];
#pragma unroll
        for (int t = 0; t < 10; ++t) cw_r[t] = cw[t];
        float cb_r = cb[0];
        const float* xb = x + (size_t)b * LIN + 4 * j0;
        for (int jj = w; jj < jc; jj += 4) {
            float a = cb_r;
#pragma unroll
            for (int t = 0; t < 10; ++t) {
                float2 bnv = bn2[4 * jj + t];
                float  xn  = fmaf(xb[4 * jj + t], bnv.x, bnv.y);
                a = fmaf(xn, cw_r[t], a);
            }
            ldsC[jj * 64 + b] = a;
        }
    }
    __syncthreads();

    // ---- proven microtile body (identical to gemm_tile after staging) ----
    int lane = tid & 63;
    int w    = tid >> 6;
    int b0   = (lane & 7) << 3;
    int d0   = (lane >> 3) << 3;

    float acc[8][8];
#pragma unroll
    for (int i = 0; i < 8; ++i)
#pragma unroll
        for (int jx = 0; jx < 8; ++jx) acc[i][jx] = 0.f;

    int js = (jc * w) >> 2;
    int je = (jc * (w + 1)) >> 2;
    for (int jj = js; jj < je; ++jj) {
        float4 c0 = *(const float4*)(ldsC + jj * 64 + b0);
        float4 c1 = *(const float4*)(ldsC + jj * 64 + b0 + 4);
        float cv[8] = {c0.x, c0.y, c0.z, c0.w, c1.x, c1.y, c1.z, c1.w};
        float wv[8];
#pragma unroll
        for (int r = 0; r < 8; ++r) wv[r] = ldsW[(d0 + r) * 101 + jj];
#pragma unroll
        for (int i = 0; i < 8; ++i)
#pragma unroll
            for (int jx = 0; jx < 8; ++jx)
                acc[i][jx] = fmaf(cv[i], wv[jx], acc[i][jx]);
    }
    __syncthreads();

    for (int p = 0; p < 2; ++p) {
        float* red = lds + w * 2304;
#pragma unroll
        for (int i = 0; i < 8; ++i)
            *(float4*)(red + (b0 + i) * 36 + (d0 >> 1)) =
                make_float4(acc[i][4*p], acc[i][4*p+1], acc[i][4*p+2], acc[i][4*p+3]);
        __syncthreads();
        for (int t = tid; t < 512; t += 256) {
            int bb = t >> 3, gg = t & 7;
            int o = bb * 36 + 4 * gg;
            float4 a0 = *(const float4*)(lds + o);
            float4 a1 = *(const float4*)(lds + 2304 + o);
            float4 a2 = *(const float4*)(lds + 4608 + o);
            float4 a3 = *(const float4*)(lds + 6912 + o);
            float4 s;
            s.x = a0.x + a1.x + a2.x + a3.x;
            s.y = a0.y + a1.y + a2.y + a3.y;
            s.z = a0.z + a1.z + a2.z + a3.z;
            s.w = a0.w + a1.w + a2.w + a3.w;
            *(float4*)(Pt + bb * 64 + 8 * gg + 4 * p) = s;
        }
        __syncthreads();
    }
}

// ---------------- K2: act-fused attention (1024 blocks, 4-way wave K-split) -
// Each block reduces the k/v partial chunks for its batch from Pp into LDS
// (bias+ReLU+in_proj inline) and its own 64 q values, then softmax as before.
__global__ __launch_bounds__(256) void k_attn(
    const float* __restrict__ Pp,
    const float* __restrict__ lbq, const float* __restrict__ lbk,
    const float* __restrict__ lbv,
    const float* __restrict__ ipw, const float* __restrict__ ipb,
    const float* __restrict__ opw, const float* __restrict__ opb,
    float* __restrict__ cfT)
{
    __shared__ float ldsKV[2048];
    __shared__ float sden[256];
    __shared__ float snum[256];
    __shared__ float rmax[4];
    __shared__ float rmin[4];
    int tid = threadIdx.x;
    int b   = blockIdx.y;
    int w   = tid >> 6;           // wave id (uniform)
    int ii  = tid & 63;
    int i   = blockIdx.x * 64 + ii;

    {   // stage kv[b]: reduce 10 partial chunks + bias + ReLU + in_proj
        float w1 = ipw[1], b1 = ipb[1], w2 = ipw[2], b2 = ipb[2];
        for (int t = tid; t < ND; t += 256) {
            int ig  = t >> 6;
            int off = (t & 63) | (b << 6);
            float s1 = 0.f, s2 = 0.f;
#pragma unroll
            for (int c = 0; c < NCHL; ++c) {
                size_t base = (((size_t)c * 3 + 1) * 16 + ig) * 4096 + off;
                s1 += Pp[base];
                s2 += Pp[base + 16 * 4096];
            }
            ldsKV[2 * t]     = fmaf(fmaxf(s1 + lbk[t], 0.f), w1, b1);
            ldsKV[2 * t + 1] = fmaf(fmaxf(s2 + lbv[t], 0.f), w2, b2);
        }
    }
    // own q value (coalesced, duplicated across the 4 waves)
    float qi = 0.f;
    if (i < ND) {
        float s0 = 0.f;
#pragma unroll
        for (int c = 0; c < NCHL; ++c)
            s0 += Pp[(((size_t)c * 3) * 16 + blockIdx.x) * 4096 + (ii | (b << 6))];
        qi = fmaf(fmaxf(s0 + lbq[i], 0.f), ipw[0], ipb[0]);
    }
    __syncthreads();

    const float2* kv2 = (const float2*)ldsKV;
    float km = -INFINITY, kn = INFINITY;
    for (int idx = tid; idx < ND; idx += 256) {
        float2 f = kv2[idx];
        km = fmaxf(km, f.x);
        kn = fminf(kn, f.x);
    }
#pragma unroll
    for (int off = 1; off < 64; off <<= 1) {
        km = fmaxf(km, __shfl_xor(km, off));
        kn = fminf(kn, __shfl_xor(kn, off));
    }
    if (ii == 0) { rmax[w] = km; rmin[w] = kn; }
    __syncthreads();
    km = fmaxf(fmaxf(rmax[0], rmax[1]), fmaxf(rmax[2], rmax[3]));
    kn = fminf(fminf(rmin[0], rmin[1]), fminf(rmin[2], rmin[3]));

    float m = (qi >= 0.f) ? qi * km : qi * kn;

    int jb = w * 250;
    float den = 0.f, num = 0.f;
#pragma unroll 2
    for (int jl = 0; jl < 250; ++jl) {
        float2 f = kv2[jb + jl];
        float e  = __expf(fmaf(qi, f.x, -m));
        den += e;
        num = fmaf(e, f.y, num);
    }
    sden[tid] = den;
    snum[tid] = num;
    __syncthreads();
    if (w == 0 && i < ND) {
        float dt = sden[ii] + sden[64 + ii] + sden[128 + ii] + sden[192 + ii];
        float nt = snum[ii] + snum[64 + ii] + snum[128 + ii] + snum[192 + ii];
        cfT[(size_t)i * 64 + b] = (nt / dt) * opw[0] + opb[0];
    }
}

// ---------------- K3: out GEMM partials -> Op (no atomics) ------------------
__global__ __launch_bounds__(256) void k_out(
    const float* __restrict__ cfT, const float* __restrict__ W,
    float* __restrict__ Op)
{
    __shared__ float lds[9216];   // staging 6464 < reduce 9216
    int egb   = blockIdx.x * 64;
    int chunk = blockIdx.y;
    int j0 = chunk * CKO;
    int jc = (ND - j0 < CKO) ? (ND - j0) : CKO;
    const float* Asrc = cfT + (size_t)j0 * 64;
    float* Pt = Op + ((size_t)chunk * 16 + blockIdx.x) * 4096;
    gemm_tile<CKO>(Asrc, W, ND, egb, j0, jc, Pt, lds);
}

// ---------------- K4: reduce Op chunks + bias -> out ------------------------
__global__ __launch_bounds__(256) void k_fin(
    const float* __restrict__ Op, const float* __restrict__ outb,
    float* __restrict__ out)
{
    int e = blockIdx.x * 256 + threadIdx.x;
    int b = blockIdx.y;
    if (e >= ND) return;
    float s = outb[e];
    size_t cell = ((size_t)(e >> 6)) * 4096 + (b << 6) + (e & 63);
    for (int c = 0; c < NCHO; ++c)
        s += Op[(size_t)c * 16 * 4096 + cell];
    out[(size_t)b * ND + e] = s;
}

extern "C" void kernel_launch(void* const* d_in, const int* in_sizes, int n_in,
                              void* d_out, int out_size, void* d_ws, size_t ws_size,
                              hipStream_t stream)
{
    const float* x    = (const float*)d_in[0];
    const float* g    = (const float*)d_in[1];
    const float* be   = (const float*)d_in[2];
    const float* mu   = (const float*)d_in[3];
    const float* va   = (const float*)d_in[4];
    const float* cwq  = (const float*)d_in[5];
    const float* cbq  = (const float*)d_in[6];
    const float* lwq  = (const float*)d_in[7];
    const float* lbq  = (const float*)d_in[8];
    const float* cwk  = (const float*)d_in[9];
    const float* cbk  = (const float*)d_in[10];
    const float* lwk  = (const float*)d_in[11];
    const float* lbk  = (const float*)d_in[12];
    const float* cwv  = (const float*)d_in[13];
    const float* cbv  = (const float*)d_in[14];
    const float* lwv  = (const float*)d_in[15];
    const float* lbv  = (const float*)d_in[16];
    const float* ipw  = (const float*)d_in[17];
    const float* ipb  = (const float*)d_in[18];
    const float* opw  = (const float*)d_in[19];
    const float* opb  = (const float*)d_in[20];
    const float* W    = (const float*)d_in[21];
    const float* outb = (const float*)d_in[22];

    float* ws  = (float*)d_ws;
    float* Pp  = ws + OFF_PP;
    float* cfT = ws + OFF_CF;
    float* Op  = ws + OFF_OP;
    float* out = (float*)d_out;

    k_lin <<<dim3(16, 3, NCHL), 256, 0, stream>>>(x, g, be, mu, va,
                                                  cwq, cbq, cwk, cbk, cwv, cbv,
                                                  lwq, lwk, lwv, Pp);
    k_attn<<<dim3(16, 64), 256, 0, stream>>>(Pp, lbq, lbk, lbv,
                                             ipw, ipb, opw, opb, cfT);
    k_out <<<dim3(16, NCHO), 256, 0, stream>>>(cfT, W, Op);
    k_fin <<<dim3(4, 64), 256, 0, stream>>>(Op, outb, out);
}

// Round 7
// 167.269 us; speedup vs baseline: 1.1776x; 1.1776x over previous
//
#include <hip/hip_runtime.h>
#include <math.h>

#define NB 64
#define LIN 4001
#define LC 998
#define ND 1000
#define EPSBN 1e-5f

#define CKL 100          // K-chunk for QKV GEMM -> 10 chunks * 48 = 480 blocks
#define NCHL 10
#define CKO 50           // K-chunk for out GEMM -> 20 chunks * 16 = 320 blocks
#define NCHO 20

// ws float offsets
#define OFF_CONVT 0u          // 3*998*64     = 191616
#define OFF_PP    191616u     // 10*3*16*4096 = 1966080
#define OFF_CF    2157696u    // 1000*64      = 64000
#define OFF_OP    2221696u    // 20*16*4096   = 1310720
// end = 3532416 floats = 14.1 MB

// ---------------- K1: fused BatchNorm + strided conv -> convT[w][j][b] ------
// lane = j position: x reads coalesced (16B-stride overlapping windows).
__global__ __launch_bounds__(256) void k_bnconv(
    const float* __restrict__ x,
    const float* __restrict__ g, const float* __restrict__ be,
    const float* __restrict__ mu, const float* __restrict__ va,
    const float* __restrict__ cwq, const float* __restrict__ cbq,
    const float* __restrict__ cwk, const float* __restrict__ cbk,
    const float* __restrict__ cwv, const float* __restrict__ cbv,
    float* __restrict__ convT)
{
    int j = blockIdx.x * 256 + threadIdx.x;
    int b = blockIdx.y;
    if (j >= LC) return;
    const float* xb = x + (size_t)b * LIN + 4 * j;
    float aq = 0.f, ak = 0.f, av = 0.f;
#pragma unroll
    for (int t = 0; t < 10; ++t) {
        int i = 4 * j + t;
        float s  = g[i] * rsqrtf(va[i] + EPSBN);
        float xn = (xb[t] - mu[i]) * s + be[i];
        aq = fmaf(xn, cwq[t], aq);
        ak = fmaf(xn, cwk[t], ak);
        av = fmaf(xn, cwv[t], av);
    }
    convT[((size_t)0 * LC + j) * 64 + b] = aq + cbq[0];
    convT[((size_t)1 * LC + j) * 64 + b] = ak + cbk[0];
    convT[((size_t)2 * LC + j) * 64 + b] = av + cbv[0];
}

// ---------------- shared GEMM microtile body (64b x 64d x CKT) --------------
template <int CKT>
__device__ __forceinline__ void gemm_tile(
    const float* __restrict__ Asrc,   // [jc][64] chunk, b-contiguous
    const float* __restrict__ Brow,   // weight base, row stride ldB
    int ldB, int dgb, int j0, int jc,
    float* __restrict__ Pt,           // output tile [64 b][64 d]
    float* lds)
{
    constexpr int LDW = CKT + 1;
    constexpr int F2R = CKT / 2;
    float* ldsC = lds;                // [CKT][64]
    float* ldsW = lds + CKT * 64;     // [64][LDW]
    int tid  = threadIdx.x;
    int lane = tid & 63;
    int w    = tid >> 6;
    int b0   = (lane & 7) << 3;
    int d0   = (lane >> 3) << 3;

    {   // stage A chunk via float4 (fully coalesced)
        const float4* src = (const float4*)Asrc;
        float4* dst = (float4*)ldsC;
        int n = jc * 16;
        for (int t = tid; t < n; t += 256) dst[t] = src[t];
    }
    // stage B tile via float2 (row starts & j0 are even)
    for (int idx = tid; idx < 64 * F2R; idx += 256) {
        int dd = idx / F2R, j2 = idx % F2R;
        int dg = dgb + dd;
        float2 v = make_float2(0.f, 0.f);
        if (dg < ND && 2 * j2 < jc)
            v = *(const float2*)(Brow + (size_t)dg * ldB + j0 + 2 * j2);
        ldsW[dd * LDW + 2 * j2]     = v.x;
        ldsW[dd * LDW + 2 * j2 + 1] = v.y;
    }
    __syncthreads();

    float acc[8][8];
#pragma unroll
    for (int i = 0; i < 8; ++i)
#pragma unroll
        for (int jx = 0; jx < 8; ++jx) acc[i][jx] = 0.f;

    int js = (jc * w) >> 2;
    int je = (jc * (w + 1)) >> 2;
    for (int jj = js; jj < je; ++jj) {
        float4 c0 = *(const float4*)(ldsC + jj * 64 + b0);
        float4 c1 = *(const float4*)(ldsC + jj * 64 + b0 + 4);
        float cv[8] = {c0.x, c0.y, c0.z, c0.w, c1.x, c1.y, c1.z, c1.w};
        float wv[8];
#pragma unroll
        for (int r = 0; r < 8; ++r) wv[r] = ldsW[(d0 + r) * LDW + jj];
#pragma unroll
        for (int i = 0; i < 8; ++i)
#pragma unroll
            for (int jx = 0; jx < 8; ++jx)
                acc[i][jx] = fmaf(cv[i], wv[jx], acc[i][jx]);
    }
    __syncthreads();   // done with staged data; reuse LDS for reduce

    // two passes (f4 halves of each lane's d-range); per-wave buf [64][36]
    for (int p = 0; p < 2; ++p) {
        float* red = lds + w * 2304;
#pragma unroll
        for (int i = 0; i < 8; ++i)
            *(float4*)(red + (b0 + i) * 36 + (d0 >> 1)) =
                make_float4(acc[i][4*p], acc[i][4*p+1], acc[i][4*p+2], acc[i][4*p+3]);
        __syncthreads();
        for (int t = tid; t < 512; t += 256) {
            int bb = t >> 3, gg = t & 7;
            int o = bb * 36 + 4 * gg;
            float4 a0 = *(const float4*)(lds + o);
            float4 a1 = *(const float4*)(lds + 2304 + o);
            float4 a2 = *(const float4*)(lds + 4608 + o);
            float4 a3 = *(const float4*)(lds + 6912 + o);
            float4 s;
            s.x = a0.x + a1.x + a2.x + a3.x;
            s.y = a0.y + a1.y + a2.y + a3.y;
            s.z = a0.z + a1.z + a2.z + a3.z;
            s.w = a0.w + a1.w + a2.w + a3.w;
            *(float4*)(Pt + bb * 64 + 8 * gg + 4 * p) = s;
        }
        __syncthreads();
    }
}

// ---------------- K2: QKV GEMM partials -> Pp (no atomics) ------------------
__global__ __launch_bounds__(256) void k_lin(
    const float* __restrict__ convT,
    const float* __restrict__ lwq, const float* __restrict__ lwk,
    const float* __restrict__ lwv,
    float* __restrict__ Pp)
{
    __shared__ float lds[12864];
    int dgb   = blockIdx.x * 64;
    int which = blockIdx.y;
    int chunk = blockIdx.z;
    int j0 = chunk * CKL;
    int jc = (LC - j0 < CKL) ? (LC - j0) : CKL;
    const float* lw = (which == 0) ? lwq : ((which == 1) ? lwk : lwv);
    const float* Asrc = convT + ((size_t)which * LC + j0) * 64;
    float* Pt = Pp + (((size_t)chunk * 3 + which) * 16 + blockIdx.x) * 4096;
    gemm_tile<CKL>(Asrc, lw, LC, dgb, j0, jc, Pt, lds);
}

// ---------------- K3: act-fused attention (1024 blocks, 4-way wave K-split) -
// Each block reduces the k/v partial chunks for its batch from Pp into LDS
// (bias+ReLU+in_proj inline) and its own 64 q values, then softmax as before.
__global__ __launch_bounds__(256) void k_attn(
    const float* __restrict__ Pp,
    const float* __restrict__ lbq, const float* __restrict__ lbk,
    const float* __restrict__ lbv,
    const float* __restrict__ ipw, const float* __restrict__ ipb,
    const float* __restrict__ opw, const float* __restrict__ opb,
    float* __restrict__ cfT)
{
    __shared__ float ldsKV[2048];
    __shared__ float sden[256];
    __shared__ float snum[256];
    __shared__ float rmax[4];
    __shared__ float rmin[4];
    int tid = threadIdx.x;
    int b   = blockIdx.y;
    int w   = tid >> 6;           // wave id (uniform)
    int ii  = tid & 63;
    int i   = blockIdx.x * 64 + ii;

    {   // stage kv[b]: reduce 10 partial chunks + bias + ReLU + in_proj
        float w1 = ipw[1], b1 = ipb[1], w2 = ipw[2], b2 = ipb[2];
        for (int t = tid; t < ND; t += 256) {
            int ig  = t >> 6;
            int off = (t & 63) | (b << 6);
            float s1 = 0.f, s2 = 0.f;
#pragma unroll
            for (int c = 0; c < NCHL; ++c) {
                size_t base = (((size_t)c * 3 + 1) * 16 + ig) * 4096 + off;
                s1 += Pp[base];
                s2 += Pp[base + 16 * 4096];
            }
            ldsKV[2 * t]     = fmaf(fmaxf(s1 + lbk[t], 0.f), w1, b1);
            ldsKV[2 * t + 1] = fmaf(fmaxf(s2 + lbv[t], 0.f), w2, b2);
        }
    }
    // own q value (coalesced, duplicated across the 4 waves)
    float qi = 0.f;
    if (i < ND) {
        float s0 = 0.f;
#pragma unroll
        for (int c = 0; c < NCHL; ++c)
            s0 += Pp[(((size_t)c * 3) * 16 + blockIdx.x) * 4096 + (ii | (b << 6))];
        qi = fmaf(fmaxf(s0 + lbq[i], 0.f), ipw[0], ipb[0]);
    }
    __syncthreads();

    const float2* kv2 = (const float2*)ldsKV;
    float km = -INFINITY, kn = INFINITY;
    for (int idx = tid; idx < ND; idx += 256) {
        float2 f = kv2[idx];
        km = fmaxf(km, f.x);
        kn = fminf(kn, f.x);
    }
#pragma unroll
    for (int off = 1; off < 64; off <<= 1) {
        km = fmaxf(km, __shfl_xor(km, off));
        kn = fminf(kn, __shfl_xor(kn, off));
    }
    if (ii == 0) { rmax[w] = km; rmin[w] = kn; }
    __syncthreads();
    km = fmaxf(fmaxf(rmax[0], rmax[1]), fmaxf(rmax[2], rmax[3]));
    kn = fminf(fminf(rmin[0], rmin[1]), fminf(rmin[2], rmin[3]));

    float m = (qi >= 0.f) ? qi * km : qi * kn;

    int jb = w * 250;
    float den = 0.f, num = 0.f;
#pragma unroll 2
    for (int jl = 0; jl < 250; ++jl) {
        float2 f = kv2[jb + jl];
        float e  = __expf(fmaf(qi, f.x, -m));
        den += e;
        num = fmaf(e, f.y, num);
    }
    sden[tid] = den;
    snum[tid] = num;
    __syncthreads();
    if (w == 0 && i < ND) {
        float dt = sden[ii] + sden[64 + ii] + sden[128 + ii] + sden[192 + ii];
        float nt = snum[ii] + snum[64 + ii] + snum[128 + ii] + snum[192 + ii];
        cfT[(size_t)i * 64 + b] = (nt / dt) * opw[0] + opb[0];
    }
}

// ---------------- K4: out GEMM partials -> Op (no atomics) ------------------
__global__ __launch_bounds__(256) void k_out(
    const float* __restrict__ cfT, const float* __restrict__ W,
    float* __restrict__ Op)
{
    __shared__ float lds[9216];   // staging 6464 < reduce 9216
    int egb   = blockIdx.x * 64;
    int chunk = blockIdx.y;
    int j0 = chunk * CKO;
    int jc = (ND - j0 < CKO) ? (ND - j0) : CKO;
    const float* Asrc = cfT + (size_t)j0 * 64;
    float* Pt = Op + ((size_t)chunk * 16 + blockIdx.x) * 4096;
    gemm_tile<CKO>(Asrc, W, ND, egb, j0, jc, Pt, lds);
}

// ---------------- K5: reduce Op chunks + bias -> out ------------------------
__global__ __launch_bounds__(256) void k_fin(
    const float* __restrict__ Op, const float* __restrict__ outb,
    float* __restrict__ out)
{
    int e = blockIdx.x * 256 + threadIdx.x;
    int b = blockIdx.y;
    if (e >= ND) return;
    float s = outb[e];
    size_t cell = ((size_t)(e >> 6)) * 4096 + (b << 6) + (e & 63);
    for (int c = 0; c < NCHO; ++c)
        s += Op[(size_t)c * 16 * 4096 + cell];
    out[(size_t)b * ND + e] = s;
}

extern "C" void kernel_launch(void* const* d_in, const int* in_sizes, int n_in,
                              void* d_out, int out_size, void* d_ws, size_t ws_size,
                              hipStream_t stream)
{
    const float* x    = (const float*)d_in[0];
    const float* g    = (const float*)d_in[1];
    const float* be   = (const float*)d_in[2];
    const float* mu   = (const float*)d_in[3];
    const float* va   = (const float*)d_in[4];
    const float* cwq  = (const float*)d_in[5];
    const float* cbq  = (const float*)d_in[6];
    const float* lwq  = (const float*)d_in[7];
    const float* lbq  = (const float*)d_in[8];
    const float* cwk  = (const float*)d_in[9];
    const float* cbk  = (const float*)d_in[10];
    const float* lwk  = (const float*)d_in[11];
    const float* lbk  = (const float*)d_in[12];
    const float* cwv  = (const float*)d_in[13];
    const float* cbv  = (const float*)d_in[14];
    const float* lwv  = (const float*)d_in[15];
    const float* lbv  = (const float*)d_in[16];
    const float* ipw  = (const float*)d_in[17];
    const float* ipb  = (const float*)d_in[18];
    const float* opw  = (const float*)d_in[19];
    const float* opb  = (const float*)d_in[20];
    const float* W    = (const float*)d_in[21];
    const float* outb = (const float*)d_in[22];

    float* ws    = (float*)d_ws;
    float* convT = ws + OFF_CONVT;
    float* Pp    = ws + OFF_PP;
    float* cfT   = ws + OFF_CF;
    float* Op    = ws + OFF_OP;
    float* out   = (float*)d_out;

    k_bnconv<<<dim3(4, 64), 256, 0, stream>>>(x, g, be, mu, va,
                                              cwq, cbq, cwk, cbk, cwv, cbv, convT);
    k_lin  <<<dim3(16, 3, NCHL), 256, 0, stream>>>(convT, lwq, lwk, lwv, Pp);
    k_attn <<<dim3(16, 64), 256, 0, stream>>>(Pp, lbq, lbk, lbv,
                                              ipw, ipb, opw, opb, cfT);
    k_out  <<<dim3(16, NCHO), 256, 0, stream>>>(cfT, W, Op);
    k_fin  <<<dim3(4, 64), 256, 0, stream>>>(Op, outb, out);
}